// Round 6
// baseline (8777.674 us; speedup 1.0000x reference)
//
#include <hip/hip_runtime.h>
#include <hip/hip_bf16.h>
#include <math.h>

// Problem constants: T=512, B=64, D=512, H=1024, O=512
constexpr int T = 512;
constexpr int B = 64;
constexpr int D = 512;
constexpr int H = 1024;
constexpr int O = 512;
constexpr int GROUPS = 2;          // independent batch groups (no cross-sync)
constexpr int BG   = B / GROUPS;   // 32 batch rows per group
constexpr int GBLK = 64;           // blocks per group (own the 4096 gate-cols)
constexpr int COLS = 64;           // gate-cols per block (16 units x 4 gates)
constexpr int KCH  = (D + H) / 8;  // 192 k-chunks of 8 elems

typedef __attribute__((ext_vector_type(8))) __bf16 bf16x8;
typedef __attribute__((ext_vector_type(4))) float  floatx4;

// Round-20 barrier: 64 packed flags per group (256 B). Lane l of every
// compute wave watches flag l directly; scalar retry until all 64 producers
// arrived; then the whole 64 KB h-burst issues with ONE final vmcnt(0).
struct GBar {
    unsigned arr[GBLK];   // flag[gb] = t+1 once block gb finished step t
};

// ---------------------------------------------------------------------------
// W' bf16: Wc[region(64)][kchunk(192)][nl6(64)][8].
// Region gb owns 64 gate-cols = 16 hidden units x 4 gates:
//   nl6 -> s=nl6>>4 (strip 0..3), jl=(nl6>>2)&3, g=nl6&3 ; j = gb*16+jl*4+s.
// For fixed jl, strips s=0..3 give CONSECUTIVE units j0..j0+3 -> epilogue
// lane owns 4 adjacent h values -> single 8B store.
// k<512 from Wx[g*H+j][k], else Wh[g*H+j][k-512].
// ---------------------------------------------------------------------------
__global__ __launch_bounds__(256) void convert_w(
    const float* __restrict__ Wx, const float* __restrict__ Wh,
    __bf16* __restrict__ Wc)
{
    const int id = blockIdx.x * 256 + threadIdx.x;   // 64*192*64 = 786432
    if (id >= GBLK * KCH * 64) return;
    const int nl6    = id & 63;
    const int kchunk = (id >> 6) % KCH;
    const int blk    = id / (KCH * 64);
    const int s  = nl6 >> 4;
    const int jl = (nl6 >> 2) & 3;
    const int g  = nl6 & 3;
    const int j  = blk * 16 + jl * 4 + s;
    const int k0 = kchunk * 8;
    const float* src = (k0 < D) ? &Wx[(size_t)(g * H + j) * D + k0]
                                : &Wh[(size_t)(g * H + j) * H + (k0 - D)];
    const float4 a = *(const float4*)src;
    const float4 b = *(const float4*)(src + 4);
    __bf16 t8[8] = {(__bf16)a.x,(__bf16)a.y,(__bf16)a.z,(__bf16)a.w,
                    (__bf16)b.x,(__bf16)b.y,(__bf16)b.z,(__bf16)b.w};
    *(uint4*)&Wc[(size_t)id * 8] = *(uint4*)t8;
}

__global__ __launch_bounds__(256) void make_bias(
    const float* __restrict__ bx, const float* __restrict__ bh,
    float* __restrict__ bias)
{
    const int n = blockIdx.x * 256 + threadIdx.x;
    if (n < 4 * H) {
        const int gbn = n >> 6, nl6 = n & 63;
        const int s  = nl6 >> 4;
        const int jl = (nl6 >> 2) & 3;
        const int g  = nl6 & 3;
        const int j  = gbn * 16 + jl * 4 + s;
        bias[n] = bx[g * H + j] + bh[g * H + j];
    }
}

// ---------------------------------------------------------------------------
// Persistent LSTM, round 20: HALVED BROADCAST.
//  64-col blocks (64 per group, 128 total): chip-wide h+x re-read traffic
//  drops from 32 MB/step to 16 MB/step (the per-block h/x read volume is
//  independent of cols; fewer blocks = less duplication).
//  - Wh-part W (128 KB) entirely in LDS (critical path unchanged).
//  - Wx-part W streamed from L2 each step in the propagation shadow
//    (read-only, XCD-local: 16 blocks x 64 KB = 1 MB per XCD L2).
//  - h-burst asm identical to R19 (verified): spin on 64 packed flags +
//    32 dwordx4 + one vmcnt(0), all in one asm block.
//  - epilogue: 4 strips; lane owns units j0..j0+3 -> one 8B h-store.
//  - hfin dropped: out_gemm reads final bf16 h from hbufs (buffer 0).
// ---------------------------------------------------------------------------
__global__ __launch_bounds__(128, 1) void lstm_persistent(
    const float* __restrict__ x,     // [T,B,D] fp32
    const __bf16* __restrict__ Wc,   // region-major bf16
    const float* __restrict__ bias,  // [4096] reordered
    __bf16* __restrict__ hbufs,      // [GROUPS][2][BG*H] bf16 ping/pong
    GBar* bars)                      // [GROUPS]
{
    __shared__ __attribute__((aligned(16))) __bf16 wlds[128 * 512]; // 128 KB Wh

    const int tid   = threadIdx.x;
    const int wid   = tid >> 6;    // wave id == m-tile (16 batch rows), 0..1
    const int lane  = tid & 63;
    const int cm    = lane & 15;
    const int q     = lane >> 4;
    const int group = blockIdx.x >> 6;          // 0..1
    const int gb    = blockIdx.x & 63;          // block within group
    const int n0    = gb * COLS;
    GBar* bar = bars + group;
    __bf16* hb0 = hbufs + (size_t)group * 2 * BG * H;
    __bf16* hb1 = hb0 + BG * H;

    // ---- one-time: Wh strip (kchunks 64..191) -> LDS, 8192 x 16B ----
    {
        const uint4* wsrc = (const uint4*)(Wc + ((size_t)gb * KCH + 64) * 512);
        uint4* wdst = (uint4*)wlds;
        for (int i = tid; i < 8192; i += 128) wdst[i] = wsrc[i];
    }
    const int p4 = cm & 3;
    const int jl = cm >> 2;
    const int row_l = wid * 16 + q * 4 + p4;     // 0..31 local batch row
    float4 biasq[4];
    #pragma unroll
    for (int s = 0; s < 4; ++s)
        biasq[s] = *(const float4*)&bias[n0 + s * 16 + jl * 4];
    float cst[4] = {0.f, 0.f, 0.f, 0.f};
    __syncthreads();

    const int grow = group * BG + wid * 16 + cm;
    const float* xrow = x + (size_t)grow * D + q * 8;
    const int    hoff = (wid * 16 + cm) * H + q * 8;   // within group h buffer
    const __bf16* wl  = wlds + q * 512 + cm * 8;       // h b-frag base (LDS)
    const __bf16* wxg = Wc + (size_t)gb * KCH * 512 + q * 512 + cm * 8; // x b-frags (global)
    const unsigned* fa = bar->arr + lane;              // lane watches 1 flag

    floatx4 acc[4];      // [col-strip]
    float4  xcur[16][2]; // prefetched x_t fragments

    auto loadx = [&](int tt) {
        const float* xr = xrow + (size_t)tt * (B * D);
        #pragma unroll
        for (int s = 0; s < 16; ++s) {
            xcur[s][0] = *(const float4*)(xr + s * 32);
            xcur[s][1] = *(const float4*)(xr + s * 32 + 4);
        }
    };
    // x-part MFMAs: B-frags streamed from L2 (read-only, latency-tolerant —
    // runs in the propagation shadow).
    auto xmfma = [&]() {
        acc[0] = (floatx4){0,0,0,0}; acc[1] = (floatx4){0,0,0,0};
        acc[2] = (floatx4){0,0,0,0}; acc[3] = (floatx4){0,0,0,0};
        #pragma unroll
        for (int s16 = 0; s16 < 16; ++s16) {
            const float4 a0 = xcur[s16][0], a1 = xcur[s16][1];
            const bf16x8 af = {(__bf16)a0.x,(__bf16)a0.y,(__bf16)a0.z,(__bf16)a0.w,
                               (__bf16)a1.x,(__bf16)a1.y,(__bf16)a1.z,(__bf16)a1.w};
            #pragma unroll
            for (int s = 0; s < 4; ++s) {
                const bf16x8 b = *(const bf16x8*)(wxg + s16 * 2048 + s * 128);
                acc[s] = __builtin_amdgcn_mfma_f32_16x16x32_bf16(af, b, acc[s], 0, 0, 0);
            }
        }
    };

    // 4x4 transpose across lane-quads: in V[r] = C[row q*4+r][gate p4],
    // out V[r] = C[row q*4+p4][gate r].   (R13-verified butterfly)
    auto quadT = [&](float v[4]) {
        float w0 = __shfl_xor(v[1], 1), w1 = __shfl_xor(v[0], 1);
        float w2 = __shfl_xor(v[3], 1), w3 = __shfl_xor(v[2], 1);
        if (p4 & 1) { v[0] = w0; v[2] = w2; } else { v[1] = w1; v[3] = w3; }
        w0 = __shfl_xor(v[2], 2); w1 = __shfl_xor(v[3], 2);
        w2 = __shfl_xor(v[0], 2); w3 = __shfl_xor(v[1], 2);
        if (p4 & 2) { v[0] = w0; v[1] = w1; } else { v[2] = w2; v[3] = w3; }
    };

    loadx(0);
    xmfma();

    for (int t = 0; t < T; ++t) {
        const __bf16* hcur = (t & 1) ? hb1 : hb0;
        __bf16*       hnxt = (t & 1) ? hb0 : hb1;

        // ---- h-part: one spin (all 64 packed flags >= t; s_sleep backoff)
        //      then the full 32-chunk burst, ONE final vmcnt(0). ----
        {
            const __bf16* hbase = hcur + hoff;   // per-lane, 16B aligned
            uint4 hv[32];
            unsigned f0t;
            asm volatile(
                "1: global_load_dword %[f0], %[fa], off sc0 sc1\n\t"
                "s_waitcnt vmcnt(0)\n\t"
                "v_cmp_gt_i32 vcc, %[tt], %[f0]\n\t"
                "s_cbranch_vccz 2f\n\t"
                "s_sleep 1\n\t"
                "s_branch 1b\n\t"
                "2: global_load_dwordx4 %[h0], %[hb], off sc0 sc1\n\t"
                "global_load_dwordx4 %[h1], %[hb], off offset:64 sc0 sc1\n\t"
                "global_load_dwordx4 %[h2], %[hb], off offset:128 sc0 sc1\n\t"
                "global_load_dwordx4 %[h3], %[hb], off offset:192 sc0 sc1\n\t"
                "global_load_dwordx4 %[h4], %[hb], off offset:256 sc0 sc1\n\t"
                "global_load_dwordx4 %[h5], %[hb], off offset:320 sc0 sc1\n\t"
                "global_load_dwordx4 %[h6], %[hb], off offset:384 sc0 sc1\n\t"
                "global_load_dwordx4 %[h7], %[hb], off offset:448 sc0 sc1\n\t"
                "global_load_dwordx4 %[h8], %[hb], off offset:512 sc0 sc1\n\t"
                "global_load_dwordx4 %[h9], %[hb], off offset:576 sc0 sc1\n\t"
                "global_load_dwordx4 %[h10], %[hb], off offset:640 sc0 sc1\n\t"
                "global_load_dwordx4 %[h11], %[hb], off offset:704 sc0 sc1\n\t"
                "global_load_dwordx4 %[h12], %[hb], off offset:768 sc0 sc1\n\t"
                "global_load_dwordx4 %[h13], %[hb], off offset:832 sc0 sc1\n\t"
                "global_load_dwordx4 %[h14], %[hb], off offset:896 sc0 sc1\n\t"
                "global_load_dwordx4 %[h15], %[hb], off offset:960 sc0 sc1\n\t"
                "global_load_dwordx4 %[h16], %[hb], off offset:1024 sc0 sc1\n\t"
                "global_load_dwordx4 %[h17], %[hb], off offset:1088 sc0 sc1\n\t"
                "global_load_dwordx4 %[h18], %[hb], off offset:1152 sc0 sc1\n\t"
                "global_load_dwordx4 %[h19], %[hb], off offset:1216 sc0 sc1\n\t"
                "global_load_dwordx4 %[h20], %[hb], off offset:1280 sc0 sc1\n\t"
                "global_load_dwordx4 %[h21], %[hb], off offset:1344 sc0 sc1\n\t"
                "global_load_dwordx4 %[h22], %[hb], off offset:1408 sc0 sc1\n\t"
                "global_load_dwordx4 %[h23], %[hb], off offset:1472 sc0 sc1\n\t"
                "global_load_dwordx4 %[h24], %[hb], off offset:1536 sc0 sc1\n\t"
                "global_load_dwordx4 %[h25], %[hb], off offset:1600 sc0 sc1\n\t"
                "global_load_dwordx4 %[h26], %[hb], off offset:1664 sc0 sc1\n\t"
                "global_load_dwordx4 %[h27], %[hb], off offset:1728 sc0 sc1\n\t"
                "global_load_dwordx4 %[h28], %[hb], off offset:1792 sc0 sc1\n\t"
                "global_load_dwordx4 %[h29], %[hb], off offset:1856 sc0 sc1\n\t"
                "global_load_dwordx4 %[h30], %[hb], off offset:1920 sc0 sc1\n\t"
                "global_load_dwordx4 %[h31], %[hb], off offset:1984 sc0 sc1\n\t"
                "s_waitcnt vmcnt(0)"
                : [h0]"=&v"(hv[0]),  [h1]"=&v"(hv[1]),  [h2]"=&v"(hv[2]),  [h3]"=&v"(hv[3]),
                  [h4]"=&v"(hv[4]),  [h5]"=&v"(hv[5]),  [h6]"=&v"(hv[6]),  [h7]"=&v"(hv[7]),
                  [h8]"=&v"(hv[8]),  [h9]"=&v"(hv[9]),  [h10]"=&v"(hv[10]), [h11]"=&v"(hv[11]),
                  [h12]"=&v"(hv[12]), [h13]"=&v"(hv[13]), [h14]"=&v"(hv[14]), [h15]"=&v"(hv[15]),
                  [h16]"=&v"(hv[16]), [h17]"=&v"(hv[17]), [h18]"=&v"(hv[18]), [h19]"=&v"(hv[19]),
                  [h20]"=&v"(hv[20]), [h21]"=&v"(hv[21]), [h22]"=&v"(hv[22]), [h23]"=&v"(hv[23]),
                  [h24]"=&v"(hv[24]), [h25]"=&v"(hv[25]), [h26]"=&v"(hv[26]), [h27]"=&v"(hv[27]),
                  [h28]"=&v"(hv[28]), [h29]"=&v"(hv[29]), [h30]"=&v"(hv[30]), [h31]"=&v"(hv[31]),
                  [f0]"=&v"(f0t)
                : [hb]"v"(hbase), [fa]"v"(fa), [tt]"v"(t)
                : "memory", "vcc");
            #pragma unroll
            for (int sg = 0; sg < 32; ++sg) {
                union { uint4 u; bf16x8 v; } hf; hf.u = hv[sg];
                #pragma unroll
                for (int s = 0; s < 4; ++s) {
                    const bf16x8 b = *(const bf16x8*)(wl + sg * 2048 + s * 128);
                    acc[s] = __builtin_amdgcn_mfma_f32_16x16x32_bf16(hf.v, b, acc[s], 0, 0, 0);
                }
            }
        }

        // ---- in-register quad transposes (one per strip) ----
        float gv[4][4];
        #pragma unroll
        for (int s = 0; s < 4; ++s) {
            gv[s][0] = acc[s].x; gv[s][1] = acc[s].y;
            gv[s][2] = acc[s].z; gv[s][3] = acc[s].w;
            quadT(gv[s]);
        }

        // ---- prefetch x for t+1 (RTT hides under the cell update) ----
        if (t + 1 < T) loadx(t + 1);

        // ---- fused cell update: lane owns (row_l, units j0..j0+3) ----
        __bf16 hq[4];
        #pragma unroll
        for (int s = 0; s < 4; ++s) {
            const float ig = 1.f / (1.f + expf(-(gv[s][0] + biasq[s].x)));
            const float fg = 1.f / (1.f + expf(-(gv[s][1] + biasq[s].y)));
            const float og = 1.f / (1.f + expf(-(gv[s][2] + biasq[s].z)));
            const float ct = tanhf(gv[s][3] + biasq[s].w);
            cst[s] = fg * cst[s] + ig * ct;
            hq[s] = (__bf16)(og * tanhf(cst[s]));
        }
        const int j0 = gb * 16 + jl * 4;     // 4 consecutive units
        const int hi = row_l * H + j0;
        union { __bf16 h4[4]; unsigned long long u; } hp;
        hp.h4[0] = hq[0]; hp.h4[1] = hq[1]; hp.h4[2] = hq[2]; hp.h4[3] = hq[3];
        __hip_atomic_store((unsigned long long*)&hnxt[hi], hp.u,
                           __ATOMIC_RELAXED, __HIP_MEMORY_SCOPE_AGENT);

        __syncthreads();  // drain all threads' h stores (vmcnt0) before arrive

        // ---- arrive: leader stores the block's packed flag ----
        if (tid == 0)
            __hip_atomic_store(&bar->arr[gb], (unsigned)(t + 1),
                               __ATOMIC_RELAXED, __HIP_MEMORY_SCOPE_AGENT);

        // ---- x MFMAs for t+1 in the propagation shadow (streams Wx) ----
        if (t + 1 < T) xmfma();
    }
}

// out[b,o] = h[b,:] . Why[o,:] + bhy[o] ; h read as bf16 from hbufs buffer 0
__global__ __launch_bounds__(256) void out_gemm(
    const __bf16* __restrict__ hbufs, const float* __restrict__ Why,
    const float* __restrict__ bhy, float* __restrict__ out)
{
    const int idx = blockIdx.x * 256 + threadIdx.x;
    if (idx >= B * O) return;
    const int b = idx / O;
    const int o = idx % O;
    const int group = b >> 5, row_l = b & 31;
    const __bf16* hb = hbufs + (size_t)group * 2 * BG * H + (size_t)row_l * H;
    const float4* wv = (const float4*)&Why[(size_t)o * H];
    float s = 0.f;
    #pragma unroll 4
    for (int k8 = 0; k8 < H / 8; ++k8) {
        union { uint4 u; bf16x8 v; } hh;
        hh.u = ((const uint4*)hb)[k8];
        const float4 w0 = wv[2 * k8];
        const float4 w1 = wv[2 * k8 + 1];
        s += (float)hh.v[0] * w0.x + (float)hh.v[1] * w0.y +
             (float)hh.v[2] * w0.z + (float)hh.v[3] * w0.w +
             (float)hh.v[4] * w1.x + (float)hh.v[5] * w1.y +
             (float)hh.v[6] * w1.z + (float)hh.v[7] * w1.w;
    }
    out[idx] = s + bhy[o];
}

extern "C" void kernel_launch(void* const* d_in, const int* in_sizes, int n_in,
                              void* d_out, int out_size, void* d_ws, size_t ws_size,
                              hipStream_t stream) {
    const float* x   = (const float*)d_in[0];
    const float* Wx  = (const float*)d_in[1];
    const float* bx  = (const float*)d_in[2];
    const float* Wh  = (const float*)d_in[3];
    const float* bh  = (const float*)d_in[4];
    const float* Why = (const float*)d_in[5];
    const float* bhy = (const float*)d_in[6];
    float* out = (float*)d_out;

    // ws layout (~12.27 MiB total, <= proven 12.90 MB):
    // Wc 12,582,912 | bias 16,384 @12,582,912 | hbufs 262,144 @12,599,296
    // bars 2 x 256 @12,861,440. No hfin (out_gemm reads bf16 hbufs), so Wc
    // is never aliased and the per-step Wx streaming reads stay safe.
    char* ws = (char*)d_ws;
    __bf16* Wc    = (__bf16*)ws;
    float*  bias  = (float*)(ws + 12582912);
    __bf16* hbufs = (__bf16*)(ws + 12599296);   // [2][2][BG*H] = 256 KB
    GBar*   bars  = (GBar*)  (ws + 12861440);   // 2 x 256 B (packed flags)

    (void)hipMemsetAsync(ws + 12599296, 0, 262144 + 2 * sizeof(GBar), stream);
    convert_w<<<3072, 256, 0, stream>>>(Wx, Wh, Wc);
    make_bias<<<16, 256, 0, stream>>>(bx, bh, bias);

    lstm_persistent<<<GROUPS * GBLK, 128, 0, stream>>>(x, Wc, bias, hbufs,
                                                       bars);

    out_gemm<<<(B * O + 255) / 256, 256, 0, stream>>>(hbufs, Why, bhy, out);
}

// Round 9
// 5756.745 us; speedup vs baseline: 1.5248x; 1.5248x over previous
//
#include <hip/hip_runtime.h>
#include <hip/hip_bf16.h>
#include <math.h>

// Problem constants: T=512, B=64, D=512, H=1024, O=512
constexpr int T = 512;
constexpr int B = 64;
constexpr int D = 512;
constexpr int H = 1024;
constexpr int O = 512;
constexpr int GROUPS = 2;          // batch groups (32 rows each)
constexpr int BG   = B / GROUPS;   // 32 batch rows per group
constexpr int NREG = 64;           // col-regions (own the 4096 gate-cols)
constexpr int COLS = 64;           // gate-cols per region (16 units x 4 gates)
constexpr int KCH  = (D + H) / 8;  // 192 k-chunks of 8 elems

typedef __attribute__((ext_vector_type(8))) __bf16 bf16x8;
typedef __attribute__((ext_vector_type(4))) float  floatx4;

// Arrival flags: one dword per (group, region); A-block leader stores t+1.
struct GBar {
    unsigned arr[NREG];
};

// ---------------------------------------------------------------------------
// W' bf16: Wc[region(64)][kchunk(192)][nl6(64)][8].   (R20-proven layout)
// Region r owns 64 gate-cols = 16 hidden units x 4 gates:
//   nl6 -> s=nl6>>4 (strip 0..3), jl=(nl6>>2)&3, g=nl6&3 ; j = r*16+jl*4+s.
// k<512 from Wx[g*H+j][k], else Wh[g*H+j][k-512].
// ---------------------------------------------------------------------------
__global__ __launch_bounds__(256) void convert_w(
    const float* __restrict__ Wx, const float* __restrict__ Wh,
    __bf16* __restrict__ Wc)
{
    const int id = blockIdx.x * 256 + threadIdx.x;   // 64*192*64 = 786432
    if (id >= NREG * KCH * 64) return;
    const int nl6    = id & 63;
    const int kchunk = (id >> 6) % KCH;
    const int blk    = id / (KCH * 64);
    const int s  = nl6 >> 4;
    const int jl = (nl6 >> 2) & 3;
    const int g  = nl6 & 3;
    const int j  = blk * 16 + jl * 4 + s;
    const int k0 = kchunk * 8;
    const float* src = (k0 < D) ? &Wx[(size_t)(g * H + j) * D + k0]
                                : &Wh[(size_t)(g * H + j) * H + (k0 - D)];
    const float4 a = *(const float4*)src;
    const float4 b = *(const float4*)(src + 4);
    __bf16 t8[8] = {(__bf16)a.x,(__bf16)a.y,(__bf16)a.z,(__bf16)a.w,
                    (__bf16)b.x,(__bf16)b.y,(__bf16)b.z,(__bf16)b.w};
    *(uint4*)&Wc[(size_t)id * 8] = *(uint4*)t8;
}

__global__ __launch_bounds__(256) void make_bias(
    const float* __restrict__ bx, const float* __restrict__ bh,
    float* __restrict__ bias)
{
    const int n = blockIdx.x * 256 + threadIdx.x;
    if (n < 4 * H) {
        const int gbn = n >> 6, nl6 = n & 63;
        const int s  = nl6 >> 4;
        const int jl = (nl6 >> 2) & 3;
        const int g  = nl6 & 3;
        const int j  = gbn * 16 + jl * 4 + s;
        bias[n] = bx[g * H + j] + bh[g * H + j];
    }
}

// ---------------------------------------------------------------------------
// Persistent LSTM, round 23 = R21 design with the compile blocker fixed:
//  B's xp-store uses 8x 8-byte __hip_atomic_store (write-through, AGENT) —
//  the R14/R20-proven visibility pattern — instead of asm with uint4
//  INPUTS (AMDGPU asm rejects multi-reg tuple inputs; outputs are fine).
//
//  x/h PRODUCER-CONSUMER SPLIT, halved h-broadcast:
//  A-blocks (bid 0..127): 64-col region, Wh (128 KB) in LDS. Per step:
//    spin(64 region flags AND xp flag) -> 64 KB h-burst + 8 KB xp read in
//    ONE asm (R19-proven pattern) -> 128 MFMAs (acc init = xp) -> epilogue
//    -> h-store -> arrive. NO x-work in the lockstep cycle.
//  B-blocks (bid 128..255): Wx (64 KB) in LDS. Produce xp(t)=x_t.Wx ahead
//    of time (x is static; B needs no h), store fp32 partials (8 KB/pair)
//    into a double-buffered exchange region aliasing the DEAD Wc head
//    (guarded by a one-time all-staged barrier), flag pf=t+1. B runs ~1
//    step ahead -> A's xp wait ~ 0.
//  WAR safety: arr>=t ==> A finished step t-1 (read h(t-1), xp(t-1));
//  B writes xp(p) only after its paired A's arr>=p-1 (slot p&1 free).
//  Accumulation order identical to R20 -> bit-identical results.
// ---------------------------------------------------------------------------
__global__ __launch_bounds__(128, 1) void lstm_persistent(
    const float* __restrict__ x,     // [T,B,D] fp32
    const __bf16* __restrict__ Wc,   // region-major bf16
    const float* __restrict__ bias,  // [4096] reordered
    __bf16* __restrict__ hbufs,      // [GROUPS][2][BG*H] bf16 ping/pong
    GBar* bars,                      // [GROUPS] arrival flags
    unsigned* pf,                    // [GROUPS*NREG] xp-ready flags
    unsigned* sflags,                // [256] staged flags
    char* pbuf)                      // xp exchange (aliases Wc head, 2 MB)
{
    __shared__ __attribute__((aligned(16))) __bf16 wlds[128 * 512]; // 128 KB

    const int tid   = threadIdx.x;
    const int wid   = tid >> 6;    // wave id == m-tile (16 batch rows), 0..1
    const int lane  = tid & 63;
    const int cm    = lane & 15;
    const int q     = lane >> 4;
    const int bid   = blockIdx.x;
    const bool isB  = bid >= 128;
    const int lb    = isB ? bid - 128 : bid;
    const int group = lb >> 6;                  // 0..1
    const int region= lb & 63;                  // col-region 0..63
    GBar* bar = bars + group;
    __bf16* hb0 = hbufs + (size_t)group * 2 * BG * H;
    __bf16* hb1 = hb0 + BG * H;
    const size_t pairIdx = (size_t)(group * NREG + region);

    // ---- one-time staging: A takes Wh (kch 64..191), B takes Wx (0..63) ----
    if (isB) {
        const uint4* wsrc = (const uint4*)(Wc + (size_t)region * KCH * 512);
        uint4* wdst = (uint4*)wlds;
        for (int i = tid; i < 4096; i += 128) wdst[i] = wsrc[i];
    } else {
        const uint4* wsrc = (const uint4*)(Wc + ((size_t)region * KCH + 64) * 512);
        uint4* wdst = (uint4*)wlds;
        for (int i = tid; i < 8192; i += 128) wdst[i] = wsrc[i];
    }
    __syncthreads();
    if (tid == 0)
        __hip_atomic_store(&sflags[bid], 1u, __ATOMIC_RELAXED,
                           __HIP_MEMORY_SCOPE_AGENT);

    if (isB) {
        // ============== B: x-projection producer ==============
        // wait until ALL 256 blocks staged (pbuf aliases Wc head)
        for (;;) {
            const unsigned a = __hip_atomic_load(&sflags[tid], __ATOMIC_RELAXED,
                                                 __HIP_MEMORY_SCOPE_AGENT);
            const unsigned b2 = __hip_atomic_load(&sflags[128 + tid], __ATOMIC_RELAXED,
                                                  __HIP_MEMORY_SCOPE_AGENT);
            if (a && b2) break;
            __builtin_amdgcn_s_sleep(1);
        }
        __syncthreads();

        const int grow = group * BG + wid * 16 + cm;
        const float* xrow = x + (size_t)grow * D + q * 8;
        const __bf16* wlB = wlds + q * 512 + cm * 8;

        float4  xcur[16][2];
        floatx4 acc[4];
        for (int p = 0; p < T; ++p) {
            // pacing: slot p&1 holds xp(p-2); paired A consumed it at arr>=p-1
            if (p >= 2) {
                while ((int)__hip_atomic_load(&bar->arr[region], __ATOMIC_RELAXED,
                                              __HIP_MEMORY_SCOPE_AGENT) < p - 1)
                    __builtin_amdgcn_s_sleep(1);
            }
            const float* xr = xrow + (size_t)p * (B * D);
            #pragma unroll
            for (int s = 0; s < 16; ++s) {
                xcur[s][0] = *(const float4*)(xr + s * 32);
                xcur[s][1] = *(const float4*)(xr + s * 32 + 4);
            }
            acc[0] = (floatx4){0,0,0,0}; acc[1] = (floatx4){0,0,0,0};
            acc[2] = (floatx4){0,0,0,0}; acc[3] = (floatx4){0,0,0,0};
            #pragma unroll
            for (int s16 = 0; s16 < 16; ++s16) {
                const float4 a0 = xcur[s16][0], a1 = xcur[s16][1];
                const bf16x8 af = {(__bf16)a0.x,(__bf16)a0.y,(__bf16)a0.z,(__bf16)a0.w,
                                   (__bf16)a1.x,(__bf16)a1.y,(__bf16)a1.z,(__bf16)a1.w};
                #pragma unroll
                for (int s = 0; s < 4; ++s) {
                    const bf16x8 b = *(const bf16x8*)(wlB + s16 * 2048 + s * 128);
                    acc[s] = __builtin_amdgcn_mfma_f32_16x16x32_bf16(af, b, acc[s], 0, 0, 0);
                }
            }
            // xp store: 8x 8-byte write-through atomic stores (compile-safe;
            // same visibility class as the proven h-store).
            unsigned long long* pb8 =
                (unsigned long long*)(pbuf + ((pairIdx * 2 + (p & 1)) * 128 + tid) * 64);
            #pragma unroll
            for (int s = 0; s < 4; ++s) {
                union { floatx4 f; unsigned long long u[2]; } au;
                au.f = acc[s];
                __hip_atomic_store(&pb8[2 * s],     au.u[0], __ATOMIC_RELAXED,
                                   __HIP_MEMORY_SCOPE_AGENT);
                __hip_atomic_store(&pb8[2 * s + 1], au.u[1], __ATOMIC_RELAXED,
                                   __HIP_MEMORY_SCOPE_AGENT);
            }
            __syncthreads();   // both waves' stores drained (vmcnt0)
            if (tid == 0)
                __hip_atomic_store(&pf[pairIdx], (unsigned)(p + 1),
                                   __ATOMIC_RELAXED, __HIP_MEMORY_SCOPE_AGENT);
        }
        return;
    }

    // ============== A: recurrent consumer ==============
    const int p4 = cm & 3;
    const int jl = cm >> 2;
    const int row_l = wid * 16 + q * 4 + p4;     // 0..31 local batch row
    const int n0 = region * COLS;
    float4 biasq[4];
    #pragma unroll
    for (int s = 0; s < 4; ++s)
        biasq[s] = *(const float4*)&bias[n0 + s * 16 + jl * 4];
    float cst[4] = {0.f, 0.f, 0.f, 0.f};

    const int hoff = (wid * 16 + cm) * H + q * 8;
    const __bf16* wl = wlds + q * 512 + cm * 8;
    const unsigned* fa  = bar->arr + lane;       // lane watches flag 'lane'
    const unsigned* pfa = pf + pairIdx;          // xp-ready flag (uniform)

    floatx4 acc[4];

    auto quadT = [&](float v[4]) {
        float w0 = __shfl_xor(v[1], 1), w1 = __shfl_xor(v[0], 1);
        float w2 = __shfl_xor(v[3], 1), w3 = __shfl_xor(v[2], 1);
        if (p4 & 1) { v[0] = w0; v[2] = w2; } else { v[1] = w1; v[3] = w3; }
        w0 = __shfl_xor(v[2], 2); w1 = __shfl_xor(v[3], 2);
        w2 = __shfl_xor(v[0], 2); w3 = __shfl_xor(v[1], 2);
        if (p4 & 2) { v[0] = w0; v[1] = w1; } else { v[2] = w2; v[3] = w3; }
    };

    for (int t = 0; t < T; ++t) {
        const __bf16* hcur = (t & 1) ? hb1 : hb0;
        __bf16*       hnxt = (t & 1) ? hb0 : hb1;
        const __bf16* hbase = hcur + hoff;
        const char* pb = pbuf + ((pairIdx * 2 + (t & 1)) * 128 + tid) * 64;

        uint4 hv[32], pv[4];
        unsigned f0t, f1t;
        asm volatile(
            // spin: all 64 region flags >= t AND pf >= t+1
            "1: global_load_dword %[f0], %[fa], off sc0 sc1\n\t"
            "global_load_dword %[f1], %[pfa], off sc0 sc1\n\t"
            "s_waitcnt vmcnt(0)\n\t"
            "v_add_u32 %[f1], -1, %[f1]\n\t"
            "v_min_i32 %[f0], %[f0], %[f1]\n\t"
            "v_cmp_gt_i32 vcc, %[tt], %[f0]\n\t"
            "s_cbranch_vccz 2f\n\t"
            "s_sleep 1\n\t"
            "s_branch 1b\n\t"
            "2: global_load_dwordx4 %[h0], %[hb], off sc0 sc1\n\t"
            "global_load_dwordx4 %[h1], %[hb], off offset:64 sc0 sc1\n\t"
            "global_load_dwordx4 %[h2], %[hb], off offset:128 sc0 sc1\n\t"
            "global_load_dwordx4 %[h3], %[hb], off offset:192 sc0 sc1\n\t"
            "global_load_dwordx4 %[h4], %[hb], off offset:256 sc0 sc1\n\t"
            "global_load_dwordx4 %[h5], %[hb], off offset:320 sc0 sc1\n\t"
            "global_load_dwordx4 %[h6], %[hb], off offset:384 sc0 sc1\n\t"
            "global_load_dwordx4 %[h7], %[hb], off offset:448 sc0 sc1\n\t"
            "global_load_dwordx4 %[h8], %[hb], off offset:512 sc0 sc1\n\t"
            "global_load_dwordx4 %[h9], %[hb], off offset:576 sc0 sc1\n\t"
            "global_load_dwordx4 %[h10], %[hb], off offset:640 sc0 sc1\n\t"
            "global_load_dwordx4 %[h11], %[hb], off offset:704 sc0 sc1\n\t"
            "global_load_dwordx4 %[h12], %[hb], off offset:768 sc0 sc1\n\t"
            "global_load_dwordx4 %[h13], %[hb], off offset:832 sc0 sc1\n\t"
            "global_load_dwordx4 %[h14], %[hb], off offset:896 sc0 sc1\n\t"
            "global_load_dwordx4 %[h15], %[hb], off offset:960 sc0 sc1\n\t"
            "global_load_dwordx4 %[h16], %[hb], off offset:1024 sc0 sc1\n\t"
            "global_load_dwordx4 %[h17], %[hb], off offset:1088 sc0 sc1\n\t"
            "global_load_dwordx4 %[h18], %[hb], off offset:1152 sc0 sc1\n\t"
            "global_load_dwordx4 %[h19], %[hb], off offset:1216 sc0 sc1\n\t"
            "global_load_dwordx4 %[h20], %[hb], off offset:1280 sc0 sc1\n\t"
            "global_load_dwordx4 %[h21], %[hb], off offset:1344 sc0 sc1\n\t"
            "global_load_dwordx4 %[h22], %[hb], off offset:1408 sc0 sc1\n\t"
            "global_load_dwordx4 %[h23], %[hb], off offset:1472 sc0 sc1\n\t"
            "global_load_dwordx4 %[h24], %[hb], off offset:1536 sc0 sc1\n\t"
            "global_load_dwordx4 %[h25], %[hb], off offset:1600 sc0 sc1\n\t"
            "global_load_dwordx4 %[h26], %[hb], off offset:1664 sc0 sc1\n\t"
            "global_load_dwordx4 %[h27], %[hb], off offset:1728 sc0 sc1\n\t"
            "global_load_dwordx4 %[h28], %[hb], off offset:1792 sc0 sc1\n\t"
            "global_load_dwordx4 %[h29], %[hb], off offset:1856 sc0 sc1\n\t"
            "global_load_dwordx4 %[h30], %[hb], off offset:1920 sc0 sc1\n\t"
            "global_load_dwordx4 %[h31], %[hb], off offset:1984 sc0 sc1\n\t"
            "global_load_dwordx4 %[p0], %[pb], off sc0 sc1\n\t"
            "global_load_dwordx4 %[p1], %[pb], off offset:16 sc0 sc1\n\t"
            "global_load_dwordx4 %[p2], %[pb], off offset:32 sc0 sc1\n\t"
            "global_load_dwordx4 %[p3], %[pb], off offset:48 sc0 sc1\n\t"
            "s_waitcnt vmcnt(0)"
            : [h0]"=&v"(hv[0]),  [h1]"=&v"(hv[1]),  [h2]"=&v"(hv[2]),  [h3]"=&v"(hv[3]),
              [h4]"=&v"(hv[4]),  [h5]"=&v"(hv[5]),  [h6]"=&v"(hv[6]),  [h7]"=&v"(hv[7]),
              [h8]"=&v"(hv[8]),  [h9]"=&v"(hv[9]),  [h10]"=&v"(hv[10]), [h11]"=&v"(hv[11]),
              [h12]"=&v"(hv[12]), [h13]"=&v"(hv[13]), [h14]"=&v"(hv[14]), [h15]"=&v"(hv[15]),
              [h16]"=&v"(hv[16]), [h17]"=&v"(hv[17]), [h18]"=&v"(hv[18]), [h19]"=&v"(hv[19]),
              [h20]"=&v"(hv[20]), [h21]"=&v"(hv[21]), [h22]"=&v"(hv[22]), [h23]"=&v"(hv[23]),
              [h24]"=&v"(hv[24]), [h25]"=&v"(hv[25]), [h26]"=&v"(hv[26]), [h27]"=&v"(hv[27]),
              [h28]"=&v"(hv[28]), [h29]"=&v"(hv[29]), [h30]"=&v"(hv[30]), [h31]"=&v"(hv[31]),
              [p0]"=&v"(pv[0]), [p1]"=&v"(pv[1]), [p2]"=&v"(pv[2]), [p3]"=&v"(pv[3]),
              [f0]"=&v"(f0t), [f1]"=&v"(f1t)
            : [hb]"v"(hbase), [fa]"v"(fa), [pfa]"v"(pfa), [pb]"v"(pb), [tt]"v"(t)
            : "memory", "vcc");

        // acc init = xp partial (x-part of the gates)
        union { uint4 u; floatx4 f; } pc0, pc1, pc2, pc3;
        pc0.u = pv[0]; pc1.u = pv[1]; pc2.u = pv[2]; pc3.u = pv[3];
        acc[0] = pc0.f; acc[1] = pc1.f; acc[2] = pc2.f; acc[3] = pc3.f;

        #pragma unroll
        for (int sg = 0; sg < 32; ++sg) {
            union { uint4 u; bf16x8 v; } hf; hf.u = hv[sg];
            #pragma unroll
            for (int s = 0; s < 4; ++s) {
                const bf16x8 b = *(const bf16x8*)(wl + sg * 2048 + s * 128);
                acc[s] = __builtin_amdgcn_mfma_f32_16x16x32_bf16(hf.v, b, acc[s], 0, 0, 0);
            }
        }

        // ---- in-register quad transposes (one per strip) ----
        float gv[4][4];
        #pragma unroll
        for (int s = 0; s < 4; ++s) {
            gv[s][0] = acc[s].x; gv[s][1] = acc[s].y;
            gv[s][2] = acc[s].z; gv[s][3] = acc[s].w;
            quadT(gv[s]);
        }

        // ---- fused cell update: lane owns (row_l, units j0..j0+3) ----
        __bf16 hq[4];
        #pragma unroll
        for (int s = 0; s < 4; ++s) {
            const float ig = 1.f / (1.f + expf(-(gv[s][0] + biasq[s].x)));
            const float fg = 1.f / (1.f + expf(-(gv[s][1] + biasq[s].y)));
            const float og = 1.f / (1.f + expf(-(gv[s][2] + biasq[s].z)));
            const float ct = tanhf(gv[s][3] + biasq[s].w);
            cst[s] = fg * cst[s] + ig * ct;
            hq[s] = (__bf16)(og * tanhf(cst[s]));
        }
        const int j0 = region * 16 + jl * 4;     // 4 consecutive units
        const int hi = row_l * H + j0;
        union { __bf16 h4[4]; unsigned long long u; } hp;
        hp.h4[0] = hq[0]; hp.h4[1] = hq[1]; hp.h4[2] = hq[2]; hp.h4[3] = hq[3];
        __hip_atomic_store((unsigned long long*)&hnxt[hi], hp.u,
                           __ATOMIC_RELAXED, __HIP_MEMORY_SCOPE_AGENT);

        __syncthreads();  // drain all threads' h stores before arrive

        if (tid == 0)
            __hip_atomic_store(&bar->arr[region], (unsigned)(t + 1),
                               __ATOMIC_RELAXED, __HIP_MEMORY_SCOPE_AGENT);
    }
}

// out[b,o] = h[b,:] . Why[o,:] + bhy[o] ; h read as bf16 from hbufs buffer 0
__global__ __launch_bounds__(256) void out_gemm(
    const __bf16* __restrict__ hbufs, const float* __restrict__ Why,
    const float* __restrict__ bhy, float* __restrict__ out)
{
    const int idx = blockIdx.x * 256 + threadIdx.x;
    if (idx >= B * O) return;
    const int b = idx / O;
    const int o = idx % O;
    const int group = b >> 5, row_l = b & 31;
    const __bf16* hb = hbufs + (size_t)group * 2 * BG * H + (size_t)row_l * H;
    const float4* wv = (const float4*)&Why[(size_t)o * H];
    float s = 0.f;
    #pragma unroll 4
    for (int k8 = 0; k8 < H / 8; ++k8) {
        union { uint4 u; bf16x8 v; } hh;
        hh.u = ((const uint4*)hb)[k8];
        const float4 w0 = wv[2 * k8];
        const float4 w1 = wv[2 * k8 + 1];
        s += (float)hh.v[0] * w0.x + (float)hh.v[1] * w0.y +
             (float)hh.v[2] * w0.z + (float)hh.v[3] * w0.w +
             (float)hh.v[4] * w1.x + (float)hh.v[5] * w1.y +
             (float)hh.v[6] * w1.z + (float)hh.v[7] * w1.w;
    }
    out[idx] = s + bhy[o];
}

extern "C" void kernel_launch(void* const* d_in, const int* in_sizes, int n_in,
                              void* d_out, int out_size, void* d_ws, size_t ws_size,
                              hipStream_t stream) {
    const float* x   = (const float*)d_in[0];
    const float* Wx  = (const float*)d_in[1];
    const float* bx  = (const float*)d_in[2];
    const float* Wh  = (const float*)d_in[3];
    const float* bh  = (const float*)d_in[4];
    const float* Why = (const float*)d_in[5];
    const float* bhy = (const float*)d_in[6];
    float* out = (float*)d_out;

    // ws layout (12.87 MB total, <= proven 12.90 MB):
    // Wc 12,582,912 | bias 16,384 @12,582,912 | hbufs 262,144 @12,599,296
    // bars 2x256 @12,861,440 | pf 512 @12,861,952 | sflags 1024 @12,862,464
    // pbuf (xp exchange, 2 MB) ALIASES Wc[0:2MB) — Wc only read during the
    // one-time LDS staging; first pbuf store is gated by the all-staged
    // barrier (sflags), so the alias is race-free.
    char* ws = (char*)d_ws;
    __bf16*   Wc     = (__bf16*)ws;
    float*    bias   = (float*)(ws + 12582912);
    __bf16*   hbufs  = (__bf16*)(ws + 12599296);   // [2][2][BG*H] = 256 KB
    GBar*     bars   = (GBar*)  (ws + 12861440);   // 2 x 256 B
    unsigned* pf     = (unsigned*)(ws + 12861952); // 128 x 4 B
    unsigned* sflags = (unsigned*)(ws + 12862464); // 256 x 4 B
    char*     pbuf   = ws;                          // aliases Wc head

    (void)hipMemsetAsync(ws + 12599296, 0, 262144 + 512 + 512 + 1024, stream);
    convert_w<<<3072, 256, 0, stream>>>(Wx, Wh, Wc);
    make_bias<<<16, 256, 0, stream>>>(bx, bh, bias);

    lstm_persistent<<<2 * NREG * 2, 128, 0, stream>>>(x, Wc, bias, hbufs,
                                                      bars, pf, sflags, pbuf);

    out_gemm<<<(B * O + 255) / 256, 256, 0, stream>>>(hbufs, Why, bhy, out);
}

// Round 10
// 3375.099 us; speedup vs baseline: 2.6007x; 1.7057x over previous
//
#include <hip/hip_runtime.h>
#include <hip/hip_bf16.h>
#include <math.h>

// Problem constants: T=512, B=64, D=512, H=1024, O=512
constexpr int T = 512;
constexpr int B = 64;
constexpr int D = 512;
constexpr int H = 1024;
constexpr int O = 512;
constexpr int GROUPS = 2;          // independent batch groups (no cross-sync)
constexpr int BG   = B / GROUPS;   // 32 batch rows per group
constexpr int GBLK = 128;          // blocks per group (own the 4096 gate-cols)
constexpr int COLS = 32;           // gate-cols per block
constexpr int KCH  = (D + H) / 8;  // 192 k-chunks of 8 elems

typedef __attribute__((ext_vector_type(8))) __bf16 bf16x8;
typedef __attribute__((ext_vector_type(4))) float  floatx4;

// Packed arrival flags, one dword per block (R19-proven).
struct GBar {
    unsigned arr[GBLK];   // flag[gb] = t+1 once block gb finished step t
};

// ---------------------------------------------------------------------------
// W' bf16, strip-major: Wc[strip(128)][kchunk(192)][nl(32)][8]. (R14 layout)
// Column reorder: nl -> s=nl>>4, jl=(nl>>2)&3, g=nl&3 ; j = gb*8 + 2*jl + s.
// k<512 from Wx[g*H+j][k], else Wh[g*H+j][k-512].
// ---------------------------------------------------------------------------
__global__ __launch_bounds__(256) void convert_w(
    const float* __restrict__ Wx, const float* __restrict__ Wh,
    __bf16* __restrict__ Wc)
{
    const int id = blockIdx.x * 256 + threadIdx.x;   // 128*192*32 = 786432
    if (id >= GBLK * KCH * COLS) return;
    const int nl     = id & 31;
    const int kchunk = (id >> 5) % KCH;
    const int strip  = id / (KCH * COLS);
    const int s  = nl >> 4;
    const int jl = (nl >> 2) & 3;
    const int g  = nl & 3;
    const int j  = strip * 8 + 2 * jl + s;
    const int k0 = kchunk * 8;
    const float* src = (k0 < D) ? &Wx[(size_t)(g * H + j) * D + k0]
                                : &Wh[(size_t)(g * H + j) * H + (k0 - D)];
    const float4 a = *(const float4*)src;
    const float4 b = *(const float4*)(src + 4);
    __bf16 t8[8] = {(__bf16)a.x,(__bf16)a.y,(__bf16)a.z,(__bf16)a.w,
                    (__bf16)b.x,(__bf16)b.y,(__bf16)b.z,(__bf16)b.w};
    *(uint4*)&Wc[(size_t)id * 8] = *(uint4*)t8;
}

__global__ __launch_bounds__(256) void make_bias(
    const float* __restrict__ bx, const float* __restrict__ bh,
    float* __restrict__ bias)
{
    const int n = blockIdx.x * 256 + threadIdx.x;
    if (n < 4 * H) {
        const int gbn = n >> 5, nl = n & 31;
        const int s  = nl >> 4;
        const int jl = (nl >> 2) & 3;
        const int g  = nl & 3;
        const int j  = gbn * 8 + 2 * jl + s;
        bias[n] = bx[g * H + j] + bh[g * H + j];
    }
}

// ---------------------------------------------------------------------------
// Persistent LSTM, round 24 = R19 core (identical math) with L2-CACHED
// h-broadcast + per-(XCD,group) invalidate:
//  - h-burst loads are `sc0` ONLY (L1-bypass, L2-cacheable): the ~16 blocks
//    of a group on one XCD share ONE 64 KB L3 fetch through their common L2
//    -> MALL line-requests drop ~16x (was 262K/step, all L2-bypassed).
//  - coherence: a runtime-elected leader per (XCD,group) spins the 128
//    region flags (sc0 sc1, R19 asm), then fence(acquire,"agent") emits
//    buffer_inv (drops stale ping-pong lines from its XCD L2; h writes are
//    write-through so L3 is always fresh), then publishes invFlag=t+1
//    (write-through). Non-leaders spin on that single flag (sc0 sc1).
//  - election: s_getreg(HW_REG_XCC_ID) [m09-verified] + atomicAdd rank;
//    96 KB LDS forces 1 block/CU -> exactly 32 blocks/XCD. No dispatch-
//    order assumptions (any per-XCD block count works).
//  WAR gate unchanged in strength: invFlag>=t+1 => leader saw all arr>=t
//  => every block finished step t-1. Stores/order identical to R19.
// ---------------------------------------------------------------------------
__global__ __launch_bounds__(128, 1) void lstm_persistent(
    const float* __restrict__ x,     // [T,B,D] fp32
    const __bf16* __restrict__ Wc,   // strip-major bf16 (read once at start)
    const float* __restrict__ bias,  // [4096] reordered
    __bf16* __restrict__ hbufs,      // [GROUPS][2][BG*H] bf16 ping/pong
    float* __restrict__ hfin,        // [B,H] fp32 final h (aliases Wc head)
    GBar* bars,                      // [GROUPS]
    unsigned* invFlag,               // [16][16] dwords, 64B-padded per slot
    unsigned* xcdCnt)                // [16] election counters
{
    __shared__ __attribute__((aligned(16))) __bf16 wlds[KCH * COLS * 8]; // 96 KB
    __shared__ int sLead, sSlot;

    const int tid   = threadIdx.x;
    const int wid   = tid >> 6;    // wave id == m-tile (16 batch rows), 0..1
    const int lane  = tid & 63;
    const int cm    = lane & 15;
    const int q     = lane >> 4;
    const int group = blockIdx.x >> 7;          // 0..1
    const int gb    = blockIdx.x & 127;         // block within group
    const int n0    = gb * COLS;
    GBar* bar = bars + group;
    __bf16* hb0 = hbufs + (size_t)group * 2 * BG * H;
    __bf16* hb1 = hb0 + BG * H;

    // runtime XCD id (uniform per block)
    unsigned xcd;
    asm volatile("s_getreg_b32 %0, hwreg(HW_REG_XCC_ID)" : "=s"(xcd));

    // ---- one-time: W strip -> LDS (6144 x 16B contiguous) ----
    {
        const uint4* wsrc = (const uint4*)(Wc + (size_t)gb * KCH * COLS * 8);
        uint4* wdst = (uint4*)wlds;
        for (int i = tid; i < KCH * COLS; i += 128) wdst[i] = wsrc[i];
    }
    if (tid == 0) {
        const int slot = ((int)(xcd & 7)) * 2 + group;   // (xcd, group)
        sSlot = slot;
        sLead = (atomicAdd(&xcdCnt[slot], 1u) == 0);
    }
    const int p4 = cm & 3;
    const int jl = cm >> 2;
    const int row_l = wid * 16 + q * 4 + p4;     // 0..31 local batch row
    const float4 bias0q = *(const float4*)&bias[n0 + jl * 4];        // strip 0
    const float4 bias1q = *(const float4*)&bias[n0 + 16 + jl * 4];   // strip 1
    float c0 = 0.f, c1 = 0.f;
    __syncthreads();
    const int isLead = sLead;
    unsigned* ivf = invFlag + sSlot * 16;        // own 64B line per slot

    // global batch row for this lane's A-fragment position
    const int grow = group * BG + wid * 16 + cm;
    const float* xrow = x + (size_t)grow * D + q * 8;
    const int    hoff = (wid * 16 + cm) * H + q * 8;   // within group h buffer
    const __bf16* wl  = wlds + (q * 32 + cm) * 8;
    const unsigned* fa = bar->arr + 2 * lane;          // leader watches 2 flags

    floatx4 acc[2][2];   // [col-strip][k-parity]
    float4  xcur[16][2]; // prefetched x_t fragments

    auto loadx = [&](int tt) {
        const float* xr = xrow + (size_t)tt * (B * D);
        #pragma unroll
        for (int s = 0; s < 16; ++s) {
            xcur[s][0] = *(const float4*)(xr + s * 32);
            xcur[s][1] = *(const float4*)(xr + s * 32 + 4);
        }
    };
    auto xmfma = [&]() {
        acc[0][0] = (floatx4){0,0,0,0}; acc[0][1] = (floatx4){0,0,0,0};
        acc[1][0] = (floatx4){0,0,0,0}; acc[1][1] = (floatx4){0,0,0,0};
        #pragma unroll
        for (int s = 0; s < 16; ++s) {
            const float4 a0 = xcur[s][0], a1 = xcur[s][1];
            const bf16x8 af = {(__bf16)a0.x,(__bf16)a0.y,(__bf16)a0.z,(__bf16)a0.w,
                               (__bf16)a1.x,(__bf16)a1.y,(__bf16)a1.z,(__bf16)a1.w};
            const bf16x8 b0 = *(const bf16x8*)(wl + s * 1024);
            const bf16x8 b1 = *(const bf16x8*)(wl + s * 1024 + 128);
            acc[0][s & 1] = __builtin_amdgcn_mfma_f32_16x16x32_bf16(af, b0, acc[0][s & 1], 0, 0, 0);
            acc[1][s & 1] = __builtin_amdgcn_mfma_f32_16x16x32_bf16(af, b1, acc[1][s & 1], 0, 0, 0);
        }
    };

    // 4x4 transpose across lane-quads (R13-verified butterfly)
    auto quadT = [&](float v[4]) {
        float w0 = __shfl_xor(v[1], 1), w1 = __shfl_xor(v[0], 1);
        float w2 = __shfl_xor(v[3], 1), w3 = __shfl_xor(v[2], 1);
        if (p4 & 1) { v[0] = w0; v[2] = w2; } else { v[1] = w1; v[3] = w3; }
        w0 = __shfl_xor(v[2], 2); w1 = __shfl_xor(v[3], 2);
        w2 = __shfl_xor(v[0], 2); w3 = __shfl_xor(v[1], 2);
        if (p4 & 2) { v[0] = w0; v[1] = w1; } else { v[2] = w2; v[3] = w3; }
    };

    loadx(0);
    xmfma();

    for (int t = 0; t < T; ++t) {
        const __bf16* hcur = (t & 1) ? hb1 : hb0;
        __bf16*       hnxt = (t & 1) ? hb0 : hb1;
        const __bf16* hbase = hcur + hoff;   // per-lane, 16B aligned

        // ---- gate ----
        if (isLead) {
            unsigned f0t, f1t;
            asm volatile(
                "1: global_load_dword %[f0], %[fa], off sc0 sc1\n\t"
                "global_load_dword %[f1], %[fa], off offset:4 sc0 sc1\n\t"
                "s_waitcnt vmcnt(0)\n\t"
                "v_min_i32 %[f0], %[f0], %[f1]\n\t"
                "v_cmp_gt_i32 vcc, %[tt], %[f0]\n\t"
                "s_cbranch_vccz 2f\n\t"
                "s_sleep 1\n\t"
                "s_branch 1b\n\t"
                "2:"
                : [f0]"=&v"(f0t), [f1]"=&v"(f1t)
                : [fa]"v"(fa), [tt]"v"(t)
                : "memory", "vcc");
            // drop stale ping-pong lines from this XCD's L2 (h is
            // write-through, so L3 is fresh); then publish.
            __builtin_amdgcn_fence(__ATOMIC_ACQUIRE, "agent");
            if (tid == 0)
                __hip_atomic_store(&ivf[0], (unsigned)(t + 1),
                                   __ATOMIC_RELAXED, __HIP_MEMORY_SCOPE_AGENT);
        } else {
            unsigned f0t;
            asm volatile(
                "1: global_load_dword %[f0], %[iv], off sc0 sc1\n\t"
                "s_waitcnt vmcnt(0)\n\t"
                "v_cmp_gt_u32 vcc, %[t1], %[f0]\n\t"
                "s_cbranch_vccz 2f\n\t"
                "s_sleep 1\n\t"
                "s_branch 1b\n\t"
                "2:"
                : [f0]"=&v"(f0t)
                : [iv]"v"(ivf), [t1]"v"(t + 1)
                : "memory", "vcc");
        }

        // ---- h-burst: 32 dwordx4, sc0 ONLY (L2-cached, XCD-deduped) ----
        {
            uint4 hv[32];
            asm volatile(
                "global_load_dwordx4 %[h0], %[hb], off sc0\n\t"
                "global_load_dwordx4 %[h1], %[hb], off offset:64 sc0\n\t"
                "global_load_dwordx4 %[h2], %[hb], off offset:128 sc0\n\t"
                "global_load_dwordx4 %[h3], %[hb], off offset:192 sc0\n\t"
                "global_load_dwordx4 %[h4], %[hb], off offset:256 sc0\n\t"
                "global_load_dwordx4 %[h5], %[hb], off offset:320 sc0\n\t"
                "global_load_dwordx4 %[h6], %[hb], off offset:384 sc0\n\t"
                "global_load_dwordx4 %[h7], %[hb], off offset:448 sc0\n\t"
                "global_load_dwordx4 %[h8], %[hb], off offset:512 sc0\n\t"
                "global_load_dwordx4 %[h9], %[hb], off offset:576 sc0\n\t"
                "global_load_dwordx4 %[h10], %[hb], off offset:640 sc0\n\t"
                "global_load_dwordx4 %[h11], %[hb], off offset:704 sc0\n\t"
                "global_load_dwordx4 %[h12], %[hb], off offset:768 sc0\n\t"
                "global_load_dwordx4 %[h13], %[hb], off offset:832 sc0\n\t"
                "global_load_dwordx4 %[h14], %[hb], off offset:896 sc0\n\t"
                "global_load_dwordx4 %[h15], %[hb], off offset:960 sc0\n\t"
                "global_load_dwordx4 %[h16], %[hb], off offset:1024 sc0\n\t"
                "global_load_dwordx4 %[h17], %[hb], off offset:1088 sc0\n\t"
                "global_load_dwordx4 %[h18], %[hb], off offset:1152 sc0\n\t"
                "global_load_dwordx4 %[h19], %[hb], off offset:1216 sc0\n\t"
                "global_load_dwordx4 %[h20], %[hb], off offset:1280 sc0\n\t"
                "global_load_dwordx4 %[h21], %[hb], off offset:1344 sc0\n\t"
                "global_load_dwordx4 %[h22], %[hb], off offset:1408 sc0\n\t"
                "global_load_dwordx4 %[h23], %[hb], off offset:1472 sc0\n\t"
                "global_load_dwordx4 %[h24], %[hb], off offset:1536 sc0\n\t"
                "global_load_dwordx4 %[h25], %[hb], off offset:1600 sc0\n\t"
                "global_load_dwordx4 %[h26], %[hb], off offset:1664 sc0\n\t"
                "global_load_dwordx4 %[h27], %[hb], off offset:1728 sc0\n\t"
                "global_load_dwordx4 %[h28], %[hb], off offset:1792 sc0\n\t"
                "global_load_dwordx4 %[h29], %[hb], off offset:1856 sc0\n\t"
                "global_load_dwordx4 %[h30], %[hb], off offset:1920 sc0\n\t"
                "global_load_dwordx4 %[h31], %[hb], off offset:1984 sc0\n\t"
                "s_waitcnt vmcnt(0)"
                : [h0]"=&v"(hv[0]),  [h1]"=&v"(hv[1]),  [h2]"=&v"(hv[2]),  [h3]"=&v"(hv[3]),
                  [h4]"=&v"(hv[4]),  [h5]"=&v"(hv[5]),  [h6]"=&v"(hv[6]),  [h7]"=&v"(hv[7]),
                  [h8]"=&v"(hv[8]),  [h9]"=&v"(hv[9]),  [h10]"=&v"(hv[10]), [h11]"=&v"(hv[11]),
                  [h12]"=&v"(hv[12]), [h13]"=&v"(hv[13]), [h14]"=&v"(hv[14]), [h15]"=&v"(hv[15]),
                  [h16]"=&v"(hv[16]), [h17]"=&v"(hv[17]), [h18]"=&v"(hv[18]), [h19]"=&v"(hv[19]),
                  [h20]"=&v"(hv[20]), [h21]"=&v"(hv[21]), [h22]"=&v"(hv[22]), [h23]"=&v"(hv[23]),
                  [h24]"=&v"(hv[24]), [h25]"=&v"(hv[25]), [h26]"=&v"(hv[26]), [h27]"=&v"(hv[27]),
                  [h28]"=&v"(hv[28]), [h29]"=&v"(hv[29]), [h30]"=&v"(hv[30]), [h31]"=&v"(hv[31])
                : [hb]"v"(hbase)
                : "memory");
            #pragma unroll
            for (int sg = 0; sg < 32; ++sg) {
                union { uint4 u; bf16x8 v; } hf; hf.u = hv[sg];
                const bf16x8 b0 = *(const bf16x8*)(wl + 16384 + sg * 1024);
                const bf16x8 b1 = *(const bf16x8*)(wl + 16384 + sg * 1024 + 128);
                acc[0][sg & 1] = __builtin_amdgcn_mfma_f32_16x16x32_bf16(hf.v, b0, acc[0][sg & 1], 0, 0, 0);
                acc[1][sg & 1] = __builtin_amdgcn_mfma_f32_16x16x32_bf16(hf.v, b1, acc[1][sg & 1], 0, 0, 0);
            }
        }
        const floatx4 av0 = acc[0][0] + acc[0][1];
        const floatx4 av1 = acc[1][0] + acc[1][1];

        // ---- in-register quad transpose ----
        float g0v[4] = {av0.x, av0.y, av0.z, av0.w};
        float g1v[4] = {av1.x, av1.y, av1.z, av1.w};
        quadT(g0v);
        quadT(g1v);

        // ---- prefetch x for t+1 (RTT hides under the cell update) ----
        if (t + 1 < T) loadx(t + 1);

        // ---- fused cell update: lane owns (row_l, j0) and (row_l, j0+1) ----
        const float i0 = 1.f / (1.f + expf(-(g0v[0] + bias0q.x)));
        const float f0 = 1.f / (1.f + expf(-(g0v[1] + bias0q.y)));
        const float o0 = 1.f / (1.f + expf(-(g0v[2] + bias0q.z)));
        const float t0 = tanhf(g0v[3] + bias0q.w);
        const float i1 = 1.f / (1.f + expf(-(g1v[0] + bias1q.x)));
        const float f1 = 1.f / (1.f + expf(-(g1v[1] + bias1q.y)));
        const float o1 = 1.f / (1.f + expf(-(g1v[2] + bias1q.z)));
        const float t1 = tanhf(g1v[3] + bias1q.w);
        c0 = f0 * c0 + i0 * t0;
        c1 = f1 * c1 + i1 * t1;
        const float hv0 = o0 * tanhf(c0);
        const float hv1 = o1 * tanhf(c1);
        const int j0 = gb * 8 + 2 * jl;      // even local j; pair (j0, j0+1)
        const int hi = row_l * H + j0;
        union { __bf16 h2[2]; unsigned u; } hp;
        hp.h2[0] = (__bf16)hv0; hp.h2[1] = (__bf16)hv1;
        __hip_atomic_store((unsigned*)&hnxt[hi], hp.u, __ATOMIC_RELAXED,
                           __HIP_MEMORY_SCOPE_AGENT);   // write-through 4B
        if (t == T - 1) {
            const int gr = group * BG + row_l;
            hfin[gr * H + j0]     = hv0;
            hfin[gr * H + j0 + 1] = hv1;
        }

        __syncthreads();  // drain all threads' h stores (vmcnt0) before arrive

        // ---- arrive: leader stores the block's packed flag ----
        if (tid == 0)
            __hip_atomic_store(&bar->arr[gb], (unsigned)(t + 1),
                               __ATOMIC_RELAXED, __HIP_MEMORY_SCOPE_AGENT);

        // ---- x MFMAs for t+1 in the propagation shadow ----
        if (t + 1 < T) xmfma();
    }
}

// out[b,o] = h[b,:] . Why[o,:] + bhy[o]
__global__ __launch_bounds__(256) void out_gemm(
    const float* __restrict__ h, const float* __restrict__ Why,
    const float* __restrict__ bhy, float* __restrict__ out)
{
    const int idx = blockIdx.x * 256 + threadIdx.x;
    if (idx >= B * O) return;
    const int b = idx / O;
    const int o = idx % O;
    const float4* hv = (const float4*)&h[(size_t)b * H];
    const float4* wv = (const float4*)&Why[(size_t)o * H];
    float s = 0.f;
    #pragma unroll 4
    for (int k = 0; k < H / 4; ++k) {
        const float4 a = hv[k];
        const float4 w = wv[k];
        s += a.x * w.x + a.y * w.y + a.z * w.z + a.w * w.w;
    }
    out[idx] = s + bhy[o];
}

extern "C" void kernel_launch(void* const* d_in, const int* in_sizes, int n_in,
                              void* d_out, int out_size, void* d_ws, size_t ws_size,
                              hipStream_t stream) {
    const float* x   = (const float*)d_in[0];
    const float* Wx  = (const float*)d_in[1];
    const float* bx  = (const float*)d_in[2];
    const float* Wh  = (const float*)d_in[3];
    const float* bh  = (const float*)d_in[4];
    const float* Why = (const float*)d_in[5];
    const float* bhy = (const float*)d_in[6];
    float* out = (float*)d_out;

    // ws layout (~12.87 MB total, <= proven 12.90 MB):
    // Wc 12,582,912 | bias 16,384 @12,582,912 | hbufs 262,144 @12,599,296
    // bars 2x512 @12,861,440 | invFlag 16x64B @12,862,464 | xcdCnt 64
    // @12,863,488. hfin (256 KB fp32) aliases Wc[0:262144) — Wc only read
    // during the one-time LDS stage, 511 barriers before any t=T-1 write.
    char* ws = (char*)d_ws;
    __bf16*   Wc      = (__bf16*)ws;
    float*    bias    = (float*)(ws + 12582912);
    __bf16*   hbufs   = (__bf16*)(ws + 12599296);   // [2][2][BG*H] = 256 KB
    GBar*     bars    = (GBar*)  (ws + 12861440);   // 2 x 512 B
    unsigned* invFlag = (unsigned*)(ws + 12862464); // 16 slots x 64 B
    unsigned* xcdCnt  = (unsigned*)(ws + 12863488); // 16 x 4 B
    float*    hfin    = (float*)ws;

    (void)hipMemsetAsync(ws + 12599296, 0, 264256, stream);
    convert_w<<<3072, 256, 0, stream>>>(Wx, Wh, Wc);
    make_bias<<<16, 256, 0, stream>>>(bx, bh, bias);

    lstm_persistent<<<GROUPS * GBLK, 128, 0, stream>>>(x, Wc, bias, hbufs,
                                                       hfin, bars, invFlag,
                                                       xcdCnt);

    out_gemm<<<(B * O + 255) / 256, 256, 0, stream>>>(hfin, Why, bhy, out);
}